// Round 1
// baseline (36951.477 us; speedup 1.0000x reference)
//
#include <hip/hip_runtime.h>
#include <hip/hip_cooperative_groups.h>

namespace cg = cooperative_groups;

constexpr int BATCH = 256;
constexpr int TT    = 1024;
constexpr int HD    = 512;
constexpr int PH    = 8;     // output-slice groups
constexpr int OSL   = 64;    // outputs per wg = HD/PH
constexpr int ROWS  = 8;     // batch rows per wg
constexpr int HPAD  = 516;   // padded h row (bank offset 4, 16B-aligned rows)
constexpr int LDS_BYTES = (HD * OSL + ROWS * HPAD) * 4;  // 131072 + 16512 = 147584

__global__ void __launch_bounds__(256, 1)
rnn_coop_kernel(const float* __restrict__ x, const float* __restrict__ Wh,
                const float* __restrict__ Wx, const float* __restrict__ bx,
                float* __restrict__ out)
{
    extern __shared__ float lds[];
    float* whsT = lds;            // [HD][OSL]: whsT[k*OSL+o] = Wh[(gh*OSL+o)*HD + k]
    float* hloc = lds + HD * OSL; // [ROWS][HPAD]

    cg::grid_group grid = cg::this_grid();

    const int tid = threadIdx.x;
    const int wid = blockIdx.x;
    const int gb  = wid & 31;   // batch group (group members: same gb => same XCD under %8 round-robin)
    const int gh  = wid >> 5;   // h-slice group

    // ---- one-time: stage transposed Wh slice into LDS (coalesced global reads) ----
    {
        const float* wsrc = Wh + (size_t)gh * OSL * HD;
        for (int idx = tid; idx < OSL * HD / 4; idx += 256) {
            int o  = idx >> 7;           // 128 float4 per output row
            int k4 = (idx & 127) * 4;
            float4 v = *(const float4*)(wsrc + o * HD + k4);
            whsT[(k4 + 0) * OSL + o] = v.x;
            whsT[(k4 + 1) * OSL + o] = v.y;
            whsT[(k4 + 2) * OSL + o] = v.z;
            whsT[(k4 + 3) * OSL + o] = v.w;
        }
    }

    // ---- init h0 in LDS; write out[0] slice ----
    for (int idx = tid; idx < ROWS * HD; idx += 256) {
        int rr = idx >> 9, cc = idx & 511;
        hloc[rr * HPAD + cc] = (cc == 0 || cc == HD / 2) ? 1.f : 0.f;
    }
    for (int idx = tid; idx < ROWS * OSL; idx += 256) {
        int rr = idx >> 6, oo = idx & 63;
        int bb = gb * ROWS + rr, ho = gh * OSL + oo;
        out[(size_t)bb * HD + ho] = (ho == 0 || ho == HD / 2) ? 1.f : 0.f;
    }
    __syncthreads();

    // ---- per-thread constants: 2 adjacent outputs of one row ----
    const int r   = tid >> 5;          // row within wg (half-wave granularity)
    const int j   = tid & 31;
    const int o0  = 2 * j;             // local output pair
    const int ho0 = gh * OSL + o0;
    const int b   = gb * ROWS + r;
    const float wx00 = Wx[ho0 * 2 + 0], wx01 = Wx[ho0 * 2 + 1], bb0 = bx[ho0];
    const float wx10 = Wx[(ho0 + 1) * 2 + 0], wx11 = Wx[(ho0 + 1) * 2 + 1], bb1 = bx[ho0 + 1];
    const float* __restrict__ xrow = x + (size_t)b * TT * 2;
    const float* __restrict__ hr   = hloc + r * HPAD;
    const float* __restrict__ wcol = whsT + o0;

    for (int t = 0; t < TT; ++t) {
        float2 xv = *(const float2*)(xrow + 2 * t);   // tiny, issue early
        float a0 = 0.f, a1 = 0.f, c0 = 0.f, c1 = 0.f; // 4 independent FMA chains
        #pragma unroll 4
        for (int k = 0; k < HD; k += 2) {
            float h0v = hr[k];                               // LDS broadcast (half-wave same addr)
            float h1v = hr[k + 1];
            float2 w0 = *(const float2*)(wcol + k * OSL);    // contiguous across lanes: conflict-free
            float2 w1 = *(const float2*)(wcol + (k + 1) * OSL);
            a0 = fmaf(h0v, w0.x, a0);
            a1 = fmaf(h0v, w0.y, a1);
            c0 = fmaf(h1v, w1.x, c0);
            c1 = fmaf(h1v, w1.y, c1);
        }
        float y0 = fmaxf(a0 + c0 + fmaf(xv.x, wx00, fmaf(xv.y, wx01, bb0)), 0.f);
        float y1 = fmaxf(a1 + c1 + fmaf(xv.x, wx10, fmaf(xv.y, wx11, bb1)), 0.f);
        float* orow = out + ((size_t)(t + 1) * BATCH + b) * HD;
        *(float2*)(orow + ho0) = make_float2(y0, y1);

        grid.sync();  // device-scope release/acquire: out[t+1] fully visible

        // reload this wg's 8 rows of h_{t+1} from out[t+1]
        const float* src = out + ((size_t)(t + 1) * BATCH + gb * ROWS) * HD;
        #pragma unroll
        for (int c = 0; c < 4; ++c) {
            int idx = c * 1024 + tid * 4;     // 4096 floats, float4 per thread per pass
            int rr = idx >> 9, cc = idx & 511;
            float4 v = *(const float4*)(src + idx);
            *(float4*)(hloc + rr * HPAD + cc) = v;  // HPAD*4 % 16 == 0: aligned
        }
        __syncthreads();
    }
}

extern "C" void kernel_launch(void* const* d_in, const int* in_sizes, int n_in,
                              void* d_out, int out_size, void* d_ws, size_t ws_size,
                              hipStream_t stream) {
    const float* x  = (const float*)d_in[0];
    const float* Wh = (const float*)d_in[1];
    const float* Wx = (const float*)d_in[2];
    const float* bx = (const float*)d_in[3];
    float* out = (float*)d_out;

    (void)hipFuncSetAttribute((const void*)rnn_coop_kernel,
                              hipFuncAttributeMaxDynamicSharedMemorySize, LDS_BYTES);

    void* args[] = { (void*)&x, (void*)&Wh, (void*)&Wx, (void*)&bx, (void*)&out };
    (void)hipLaunchCooperativeKernel((const void*)rnn_coop_kernel,
                                     dim3(PH * 32), dim3(256), args, LDS_BYTES, stream);
}

// Round 2
// 20434.760 us; speedup vs baseline: 1.8083x; 1.8083x over previous
//
#include <hip/hip_runtime.h>
#include <hip/hip_cooperative_groups.h>

constexpr int BATCH = 256;
constexpr int TT    = 1024;
constexpr int HD    = 512;
constexpr int PH    = 8;     // h-slice groups (wgs per batch group)
constexpr int OSL   = 64;    // outputs per wg
constexpr int ROWS  = 8;     // batch rows per wg
constexpr int HPAD  = 516;   // padded h row (floats); 516*4B % 16 == 0
constexpr int LDS_BYTES   = (HD * OSL + ROWS * HPAD) * 4;  // 131072 + 16512 = 147584
constexpr int FLAG_STRIDE = 32;                            // uints: one 128B line per wg
constexpr int FLAG_BYTES  = 256 * FLAG_STRIDE * 4;         // 32 KB

__global__ void __launch_bounds__(256, 1)
rnn_flag_kernel(const float* __restrict__ x, const float* __restrict__ Wh,
                const float* __restrict__ Wx, const float* __restrict__ bx,
                float* __restrict__ out, uint32_t* __restrict__ flags)
{
    extern __shared__ float lds[];
    float* whsT = lds;            // [HD][OSL] : whsT[k*64+o] = Wh[gh*64+o][k]
    float* hloc = lds + HD * OSL; // [ROWS][HPAD]

    const int tid = threadIdx.x;
    const int wid = blockIdx.x;
    const int gb  = wid & 31;     // batch group; peers wid = gb + 32*gh' share XCD (perf only)
    const int gh  = wid >> 5;     // h-slice group

    // ---- one-time: stage transposed Wh slice ----
    {
        const float* wsrc = Wh + (size_t)gh * OSL * HD;
        for (int idx = tid; idx < OSL * HD / 4; idx += 256) {
            int o  = idx >> 7;
            int k4 = (idx & 127) * 4;
            float4 v = *(const float4*)(wsrc + o * HD + k4);
            whsT[(k4 + 0) * OSL + o] = v.x;
            whsT[(k4 + 1) * OSL + o] = v.y;
            whsT[(k4 + 2) * OSL + o] = v.z;
            whsT[(k4 + 3) * OSL + o] = v.w;
        }
    }
    // ---- h0 in LDS; out[0] slice ----
    for (int idx = tid; idx < ROWS * HD; idx += 256) {
        int rr = idx >> 9, cc = idx & 511;
        hloc[rr * HPAD + cc] = (cc == 0 || cc == HD / 2) ? 1.f : 0.f;
    }
    for (int idx = tid; idx < ROWS * OSL; idx += 256) {
        int rr = idx >> 6, oo = idx & 63;
        int bb = gb * ROWS + rr, ho = gh * OSL + oo;
        out[(size_t)bb * HD + ho] = (ho == 0 || ho == HD / 2) ? 1.f : 0.f;
    }
    __syncthreads();

    // ---- thread mapping: 4 outputs x 2 rows x 128 k ----
    const int lane = tid & 63;
    const int wv   = tid >> 6;        // wave 0..3 -> rows wv*2, wv*2+1
    const int og   = lane & 15;       // output quad
    const int kc   = lane >> 4;       // k-chunk 0..3 (within wave -> shfl reduce)
    const int r0   = wv * 2;
    const int o0   = og * 4;
    const int ho0  = gh * OSL + o0;

    const float wxa0 = Wx[(ho0 + 0) * 2], wxb0 = Wx[(ho0 + 0) * 2 + 1], bq0 = bx[ho0 + 0];
    const float wxa1 = Wx[(ho0 + 1) * 2], wxb1 = Wx[(ho0 + 1) * 2 + 1], bq1 = bx[ho0 + 1];
    const float wxa2 = Wx[(ho0 + 2) * 2], wxb2 = Wx[(ho0 + 2) * 2 + 1], bq2 = bx[ho0 + 2];
    const float wxa3 = Wx[(ho0 + 3) * 2], wxb3 = Wx[(ho0 + 3) * 2 + 1], bq3 = bx[ho0 + 3];

    const bool doEp = (kc < 2);           // kc0 -> row r0, kc1 -> row r0+1
    const int  rEp  = r0 + (kc & 1);
    const int  bEp  = gb * ROWS + rEp;
    const float* xrowEp = x + (size_t)bEp * TT * 2;

    const float4* wr  = (const float4*)whsT + og;  // row k at wr[k*16]
    const float*  h0p = hloc + r0 * HPAD;
    const float*  h1p = h0p + HPAD;
    const int     kb  = kc * 128;

    // exchange mapping: thread loads float2 of 7 peer chunks
    const int rLd  = tid >> 5;
    const int ccLd = (tid & 31) * 2;
    uint32_t* myFlag = flags + (size_t)(gb * PH + gh) * FLAG_STRIDE;

    for (int t = 0; t < TT; ++t) {
        float2 xv = make_float2(0.f, 0.f);
        if (doEp) xv = *(const float2*)(xrowEp + 2 * t);   // hidden under k-loop

        float a00 = 0.f, a01 = 0.f, a02 = 0.f, a03 = 0.f;
        float a10 = 0.f, a11 = 0.f, a12 = 0.f, a13 = 0.f;
        #pragma unroll 4
        for (int ki = 0; ki < 128; ki += 2) {
            const int k = kb + ki;
            float2 h0 = *(const float2*)(h0p + k);     // broadcast across 16 lanes
            float2 h1 = *(const float2*)(h1p + k);
            float4 w0 = wr[(k + 0) * 16];              // 16 lanes x 16B contiguous
            float4 w1 = wr[(k + 1) * 16];
            a00 = fmaf(h0.x, w0.x, a00); a01 = fmaf(h0.x, w0.y, a01);
            a02 = fmaf(h0.x, w0.z, a02); a03 = fmaf(h0.x, w0.w, a03);
            a10 = fmaf(h1.x, w0.x, a10); a11 = fmaf(h1.x, w0.y, a11);
            a12 = fmaf(h1.x, w0.z, a12); a13 = fmaf(h1.x, w0.w, a13);
            a00 = fmaf(h0.y, w1.x, a00); a01 = fmaf(h0.y, w1.y, a01);
            a02 = fmaf(h0.y, w1.z, a02); a03 = fmaf(h0.y, w1.w, a03);
            a10 = fmaf(h1.y, w1.x, a10); a11 = fmaf(h1.y, w1.y, a11);
            a12 = fmaf(h1.y, w1.z, a12); a13 = fmaf(h1.y, w1.w, a13);
        }
        // reduce 4 k-chunks (lane bits 4,5)
        a00 += __shfl_xor(a00, 16); a00 += __shfl_xor(a00, 32);
        a01 += __shfl_xor(a01, 16); a01 += __shfl_xor(a01, 32);
        a02 += __shfl_xor(a02, 16); a02 += __shfl_xor(a02, 32);
        a03 += __shfl_xor(a03, 16); a03 += __shfl_xor(a03, 32);
        a10 += __shfl_xor(a10, 16); a10 += __shfl_xor(a10, 32);
        a11 += __shfl_xor(a11, 16); a11 += __shfl_xor(a11, 32);
        a12 += __shfl_xor(a12, 16); a12 += __shfl_xor(a12, 32);
        a13 += __shfl_xor(a13, 16); a13 += __shfl_xor(a13, 32);

        if (doEp) {
            const float s0 = kc ? a10 : a00;
            const float s1 = kc ? a11 : a01;
            const float s2 = kc ? a12 : a02;
            const float s3 = kc ? a13 : a03;
            float y0 = fmaxf(fmaf(xv.x, wxa0, fmaf(xv.y, wxb0, bq0)) + s0, 0.f);
            float y1 = fmaxf(fmaf(xv.x, wxa1, fmaf(xv.y, wxb1, bq1)) + s1, 0.f);
            float y2 = fmaxf(fmaf(xv.x, wxa2, fmaf(xv.y, wxb2, bq2)) + s2, 0.f);
            float y3 = fmaxf(fmaf(xv.x, wxa3, fmaf(xv.y, wxb3, bq3)) + s3, 0.f);
            float4 yv = make_float4(y0, y1, y2, y3);
            *(float4*)(out + ((size_t)(t + 1) * BATCH + bEp) * HD + ho0) = yv;
            *(float4*)(hloc + rEp * HPAD + gh * OSL + o0) = yv;   // own chunk: no reload
        }

        if (t + 1 < TT) {
            __syncthreads();  // all stores drained (vmcnt 0) before publish
            if (tid == 64) {  // wave 1 publishes...
                __hip_atomic_store(myFlag, (uint32_t)(t + 1),
                                   __ATOMIC_RELEASE, __HIP_MEMORY_SCOPE_AGENT);
            }
            if (tid < 7) {    // ...wave 0 polls 7 peers concurrently
                uint32_t* pf = flags + (size_t)(gb * PH + ((gh + 1 + tid) & 7)) * FLAG_STRIDE;
                while (__hip_atomic_load(pf, __ATOMIC_ACQUIRE,
                                         __HIP_MEMORY_SCOPE_AGENT) < (uint32_t)(t + 1))
                    __builtin_amdgcn_s_sleep(2);
            }
            __syncthreads();
            __builtin_amdgcn_fence(__ATOMIC_ACQUIRE, "agent");  // invalidate stale caches
            const float* src = out + ((size_t)(t + 1) * BATCH + gb * ROWS + rLd) * HD + ccLd;
            float*       dst = hloc + rLd * HPAD + ccLd;
            #pragma unroll
            for (int p = 0; p < 7; ++p) {
                int ghp = (gh + 1 + p) & 7;
                float2 v = *(const float2*)(src + ghp * OSL);
                *(float2*)(dst + ghp * OSL) = v;
            }
            __syncthreads();
        }
    }
}

extern "C" void kernel_launch(void* const* d_in, const int* in_sizes, int n_in,
                              void* d_out, int out_size, void* d_ws, size_t ws_size,
                              hipStream_t stream) {
    const float* x  = (const float*)d_in[0];
    const float* Wh = (const float*)d_in[1];
    const float* Wx = (const float*)d_in[2];
    const float* bx = (const float*)d_in[3];
    float* out = (float*)d_out;
    uint32_t* flags = (uint32_t*)d_ws;

    (void)hipMemsetAsync(d_ws, 0, FLAG_BYTES, stream);   // flags = 0 every launch (deterministic)

    (void)hipFuncSetAttribute((const void*)rnn_flag_kernel,
                              hipFuncAttributeMaxDynamicSharedMemorySize, LDS_BYTES);

    void* args[] = { (void*)&x, (void*)&Wh, (void*)&Wx, (void*)&bx, (void*)&out, (void*)&flags };
    // cooperative launch only for the co-residency guarantee (no grid.sync inside)
    (void)hipLaunchCooperativeKernel((const void*)rnn_flag_kernel,
                                     dim3(PH * 32), dim3(256), args, LDS_BYTES, stream);
}

// Round 6
// 10019.792 us; speedup vs baseline: 3.6878x; 2.0394x over previous
//
#include <hip/hip_runtime.h>

typedef float f32x2 __attribute__((ext_vector_type(2)));
typedef float f32x4 __attribute__((ext_vector_type(4)));

constexpr int BATCH = 256;
constexpr int TT    = 1024;
constexpr int HD    = 512;
constexpr int NT    = 32;    // outputs per wg tile
constexpr int MT    = 16;    // batch rows per wg tile
// LDS: whT2 [256 k2][32 o] f32x2 = 64KB  +  h [16][512] f32 = 32KB
constexpr int LDS_BYTES = (256 * 32 * 2 + MT * HD) * 4;   // 98304

__global__ void __launch_bounds__(256, 1)
init_kernel(float* __restrict__ out)
{
    // write out[0] = h0 pattern: 1 at k==0 and k==256, else 0. 256x512 floats.
    int gid  = blockIdx.x * 256 + threadIdx.x;   // 32768 float4 slots
    int base = gid * 4;
    int k    = base & 511;
    f32x4 v = {0.f, 0.f, 0.f, 0.f};
    if (k == 0 || k == 256) v.x = 1.f;
    *(f32x4*)(out + base) = v;
}

__global__ void __launch_bounds__(256, 1)
step_kernel(const float* __restrict__ x, const float* __restrict__ Wh,
            const float* __restrict__ Wx, const float* __restrict__ bx,
            float* __restrict__ out, int t)
{
    extern __shared__ float lds[];
    f32x2* whT2 = (f32x2*)lds;          // [k2][o] : whT2[k2*32+o] = (Wh[o0+o][2k2], Wh[o0+o][2k2+1])
    float* hld  = lds + 256 * 32 * 2;   // [MT][512]

    const int tid = threadIdx.x;
    const int o0  = blockIdx.x * NT;
    const int b0  = blockIdx.y * MT;

    // ---- stage h tile (coalesced float4) ----
    const float* hsrc = out + (size_t)t * BATCH * HD + (size_t)b0 * HD;
    #pragma unroll
    for (int i = 0; i < MT * HD / 4 / 256; ++i) {
        int idx = (i * 256 + tid) * 4;
        *(f32x4*)(hld + idx) = *(const f32x4*)(hsrc + idx);
    }
    // ---- stage Wh strip, lane=o mapping (conflict-free LDS writes; strided global -> L2) ----
    {
        const int o = tid & 31, j = tid >> 5;
        const float* wr = Wh + (size_t)(o0 + o) * HD;
        #pragma unroll
        for (int i = 0; i < 16; ++i) {
            int k4 = j * 16 + i;
            f32x4 v = *(const f32x4*)(wr + k4 * 4);
            whT2[(k4 * 2 + 0) * 32 + o] = (f32x2){v.x, v.y};
            whT2[(k4 * 2 + 1) * 32 + o] = (f32x2){v.z, v.w};
        }
    }
    __syncthreads();

    // ---- compute: thread = 1 output x 2 rows, 4 independent FMA chains ----
    const int o  = tid & 31;
    const int rg = tid >> 5;                 // 8 row-groups x 2 rows
    const float* h0 = hld + (rg * 2 + 0) * HD;
    const float* h1 = hld + (rg * 2 + 1) * HD;
    const f32x2* wp = whT2 + o;

    float a00 = 0.f, a01 = 0.f, a10 = 0.f, a11 = 0.f;
    #pragma unroll 8
    for (int k2 = 0; k2 < 256; ++k2) {
        f32x2 w = wp[k2 * 32];
        f32x2 p = *(const f32x2*)(h0 + k2 * 2);
        f32x2 q = *(const f32x2*)(h1 + k2 * 2);
        a00 = fmaf(p.x, w.x, a00); a01 = fmaf(p.y, w.y, a01);
        a10 = fmaf(q.x, w.x, a10); a11 = fmaf(q.y, w.y, a11);
    }

    const int oo = o0 + o;
    const f32x2 wx = *(const f32x2*)(Wx + oo * 2);
    const float bb = bx[oo];
    const int   br = b0 + rg * 2;
    f32x2 xv0 = *(const f32x2*)(x + ((size_t)(br + 0) * TT + t) * 2);
    f32x2 xv1 = *(const f32x2*)(x + ((size_t)(br + 1) * TT + t) * 2);
    float y0 = fmaxf(a00 + a01 + fmaf(xv0.x, wx.x, fmaf(xv0.y, wx.y, bb)), 0.f);
    float y1 = fmaxf(a10 + a11 + fmaf(xv1.x, wx.x, fmaf(xv1.y, wx.y, bb)), 0.f);

    float* od = out + (size_t)(t + 1) * BATCH * HD;
    od[(size_t)(br + 0) * HD + oo] = y0;
    od[(size_t)(br + 1) * HD + oo] = y1;
}

extern "C" void kernel_launch(void* const* d_in, const int* in_sizes, int n_in,
                              void* d_out, int out_size, void* d_ws, size_t ws_size,
                              hipStream_t stream) {
    const float* x  = (const float*)d_in[0];
    const float* Wh = (const float*)d_in[1];
    const float* Wx = (const float*)d_in[2];
    const float* bx = (const float*)d_in[3];
    float* out = (float*)d_out;

    (void)hipFuncSetAttribute((const void*)step_kernel,
                              hipFuncAttributeMaxDynamicSharedMemorySize, LDS_BYTES);

    init_kernel<<<dim3(BATCH * HD / 4 / 256), dim3(256), 0, stream>>>(out);

    for (int t = 0; t < TT; ++t) {
        step_kernel<<<dim3(HD / NT, BATCH / MT), dim3(256), LDS_BYTES, stream>>>(
            x, Wh, Wx, bx, out, t);
    }
}

// Round 7
// 5643.061 us; speedup vs baseline: 6.5481x; 1.7756x over previous
//
#include <hip/hip_runtime.h>

typedef float  f32x2 __attribute__((ext_vector_type(2)));
typedef float  f32x4 __attribute__((ext_vector_type(4)));
typedef short  s16x8 __attribute__((ext_vector_type(8)));
typedef unsigned int uint;
typedef unsigned short ushort;

constexpr int BATCH = 256;
constexpr int TT    = 1024;
constexpr int HD    = 512;
constexpr int MT    = 16;                 // rows per wg
constexpr int NT    = 32;                 // outs per wg
constexpr int A_SZ  = MT * HD * 2;        // 16384 B per split
constexpr int B_SZ  = NT * HD * 2;        // 32768 B per split
constexpr int LDS_BYTES = 3 * A_SZ + 3 * B_SZ;      // 147456
constexpr int WSPLIT_BYTES = 3 * HD * HD * 2;       // 1572864 (pre-split W in d_ws)

// fp32 -> bf16 RNE (bit trick; values finite)
__device__ __forceinline__ ushort f2bf(float f) {
    uint u = __float_as_uint(f);
    return (ushort)((u + 0x7fffu + ((u >> 16) & 1u)) >> 16);
}
__device__ __forceinline__ float bf2f(ushort b) {
    return __uint_as_float((uint)b << 16);
}
// split v = hi + mid + lo (each bf16); residual ~2^-25 rel
__device__ __forceinline__ void split3(float v, ushort& h, ushort& m, ushort& l) {
    h = f2bf(v);
    float r1 = v - bf2f(h);
    m = f2bf(r1);
    float r2 = r1 - bf2f(m);
    l = f2bf(r2);
}
// swizzled byte offset within a [rows][512] bf16 region (16-way-conflict killer)
__device__ __forceinline__ uint swz(uint r, uint k) {
    return (r * 1024u + k * 2u) ^ (((r ^ (k >> 6)) & 7u) << 4);
}

__global__ void __launch_bounds__(256, 1)
init_kernel(float* __restrict__ out)
{
    int base = (blockIdx.x * 256 + threadIdx.x) * 4;
    int k = base & 511;
    f32x4 v = {0.f, 0.f, 0.f, 0.f};
    if (k == 0 || k == 256) v.x = 1.f;
    *(f32x4*)(out + base) = v;
}

// one-time: Wh fp32 -> 3 bf16 splits, PRE-SWIZZLED per 32-out strip, into d_ws
__global__ void __launch_bounds__(256, 1)
wsplit_kernel(const float* __restrict__ Wh, ushort* __restrict__ wpre)
{
    int id = blockIdx.x * 256 + threadIdx.x;   // 32768 ids: o(512) x k8(64)
    int o  = id >> 6;
    int k0 = (id & 63) * 8;
    int strip = o >> 5, col = o & 31;
    f32x4 v0 = *(const f32x4*)(Wh + (size_t)o * HD + k0);
    f32x4 v1 = *(const f32x4*)(Wh + (size_t)o * HD + k0 + 4);
    float vv[8] = {v0.x, v0.y, v0.z, v0.w, v1.x, v1.y, v1.z, v1.w};
    s16x8 ph, pm, pl;
    #pragma unroll
    for (int j = 0; j < 8; ++j) {
        ushort h, m, l; split3(vv[j], h, m, l);
        ph[j] = (short)h; pm[j] = (short)m; pl[j] = (short)l;
    }
    char* base = (char*)wpre + (size_t)strip * B_SZ;
    uint  off  = swz((uint)col, (uint)k0);
    *(s16x8*)(base + 0u * 524288u + off) = ph;
    *(s16x8*)(base + 1u * 524288u + off) = pm;
    *(s16x8*)(base + 2u * 524288u + off) = pl;
}

__global__ void __launch_bounds__(256, 1)
step_kernel(const float* __restrict__ x, const float* __restrict__ Wh,
            const float* __restrict__ Wx, const float* __restrict__ bx,
            float* __restrict__ out, const ushort* __restrict__ wpre, int t)
{
    extern __shared__ char lds[];
    char* Areg = lds;                 // 3 x [16][512] bf16, swizzled
    char* Breg = lds + 3 * A_SZ;      // 3 x [32][512] bf16, swizzled

    const int tid = threadIdx.x;
    const int o0  = blockIdx.x * NT;
    const int b0  = blockIdx.y * MT;

    // ---- stage A: h rows from out[t], convert fp32 -> bf16x3 ----
    {
        const int row = tid >> 4, kb = (tid & 15) * 32;
        const float* src = out + ((size_t)t * BATCH + b0 + row) * HD + kb;
        #pragma unroll
        for (int g = 0; g < 4; ++g) {
            f32x4 v0 = *(const f32x4*)(src + g * 8);
            f32x4 v1 = *(const f32x4*)(src + g * 8 + 4);
            float vv[8] = {v0.x, v0.y, v0.z, v0.w, v1.x, v1.y, v1.z, v1.w};
            s16x8 ph, pm, pl;
            #pragma unroll
            for (int j = 0; j < 8; ++j) {
                ushort h, m, l; split3(vv[j], h, m, l);
                ph[j] = (short)h; pm[j] = (short)m; pl[j] = (short)l;
            }
            uint off = swz((uint)row, (uint)(kb + g * 8));
            *(s16x8*)(Areg + 0 * A_SZ + off) = ph;
            *(s16x8*)(Areg + 1 * A_SZ + off) = pm;
            *(s16x8*)(Areg + 2 * A_SZ + off) = pl;
        }
    }
    // ---- stage B: pre-split path = pure copy; fallback = convert from Wh ----
    if (wpre) {
        const char* src = (const char*)wpre + (size_t)blockIdx.x * B_SZ;
        #pragma unroll
        for (int c = 0; c < 24; ++c) {            // 6144 x 16B slots total
            uint slot = (uint)(c * 256 + tid);
            uint byte = slot * 16u;
            uint split = byte >> 15, off = byte & 32767u;
            *(s16x8*)(Breg + byte) =
                *(const s16x8*)(src + (size_t)split * 524288u + off);
        }
    } else {
        const int o = tid >> 3, kb = (tid & 7) * 64;
        const float* src = Wh + (size_t)(o0 + o) * HD + kb;
        #pragma unroll
        for (int g = 0; g < 8; ++g) {
            f32x4 v0 = *(const f32x4*)(src + g * 8);
            f32x4 v1 = *(const f32x4*)(src + g * 8 + 4);
            float vv[8] = {v0.x, v0.y, v0.z, v0.w, v1.x, v1.y, v1.z, v1.w};
            s16x8 ph, pm, pl;
            #pragma unroll
            for (int j = 0; j < 8; ++j) {
                ushort h, m, l; split3(vv[j], h, m, l);
                ph[j] = (short)h; pm[j] = (short)m; pl[j] = (short)l;
            }
            uint off = swz((uint)o, (uint)(kb + g * 8));
            *(s16x8*)(Breg + 0 * B_SZ + off) = ph;
            *(s16x8*)(Breg + 1 * B_SZ + off) = pm;
            *(s16x8*)(Breg + 2 * B_SZ + off) = pl;
        }
    }
    __syncthreads();

    // ---- K-loop: wave = (nt = tid>>7) N-tile, (kw = (tid>>6)&1) K-half ----
    const int lane = tid & 63;
    const int kw   = (tid >> 6) & 1;
    const int nt   = tid >> 7;
    const int mn   = lane & 15;          // A-row / B-col
    const int koct = lane >> 4;
    const uint bcol = (uint)(nt * 16 + mn);

    f32x4 acc = {0.f, 0.f, 0.f, 0.f};
    #pragma unroll
    for (int it = 0; it < 8; ++it) {
        const uint kl = (uint)(kw * 256 + it * 32 + koct * 8);
        const uint ab = swz((uint)mn, kl);
        const uint bb = swz(bcol, kl);
        s16x8 Ah = *(const s16x8*)(Areg + 0 * A_SZ + ab);
        s16x8 Am = *(const s16x8*)(Areg + 1 * A_SZ + ab);
        s16x8 Al = *(const s16x8*)(Areg + 2 * A_SZ + ab);
        s16x8 Bh = *(const s16x8*)(Breg + 0 * B_SZ + bb);
        s16x8 Bm = *(const s16x8*)(Breg + 1 * B_SZ + bb);
        s16x8 Bl = *(const s16x8*)(Breg + 2 * B_SZ + bb);
        acc = __builtin_amdgcn_mfma_f32_16x16x32_bf16(Ah, Bh, acc, 0, 0, 0);
        acc = __builtin_amdgcn_mfma_f32_16x16x32_bf16(Ah, Bm, acc, 0, 0, 0);
        acc = __builtin_amdgcn_mfma_f32_16x16x32_bf16(Am, Bh, acc, 0, 0, 0);
        acc = __builtin_amdgcn_mfma_f32_16x16x32_bf16(Ah, Bl, acc, 0, 0, 0);
        acc = __builtin_amdgcn_mfma_f32_16x16x32_bf16(Al, Bh, acc, 0, 0, 0);
        acc = __builtin_amdgcn_mfma_f32_16x16x32_bf16(Am, Bm, acc, 0, 0, 0);
    }

    // ---- reduce K-halves via LDS scratch (aliases A region) ----
    __syncthreads();
    float* red = (float*)lds;            // 2 tiles x 64 lanes x 4 = 2KB
    if (kw == 1) *(f32x4*)(red + (nt * 64 + lane) * 4) = acc;
    __syncthreads();
    if (kw == 0) {
        f32x4 p = *(const f32x4*)(red + (nt * 64 + lane) * 4);
        acc += p;
        const int col = o0 + nt * 16 + mn;
        const f32x2 wx = *(const f32x2*)(Wx + col * 2);
        const float bb = bx[col];
        #pragma unroll
        for (int r = 0; r < 4; ++r) {
            const int b = b0 + koct * 4 + r;       // C/D: row=(lane>>4)*4+reg (m89)
            f32x2 xv = *(const f32x2*)(x + ((size_t)b * TT + t) * 2);
            float y = fmaxf(acc[r] + fmaf(xv.x, wx.x, fmaf(xv.y, wx.y, bb)), 0.f);
            out[((size_t)(t + 1) * BATCH + b) * HD + col] = y;
        }
    }
}

extern "C" void kernel_launch(void* const* d_in, const int* in_sizes, int n_in,
                              void* d_out, int out_size, void* d_ws, size_t ws_size,
                              hipStream_t stream) {
    const float* x  = (const float*)d_in[0];
    const float* Wh = (const float*)d_in[1];
    const float* Wx = (const float*)d_in[2];
    const float* bx = (const float*)d_in[3];
    float* out = (float*)d_out;

    const bool usePre = (ws_size >= (size_t)WSPLIT_BYTES);
    ushort* wpre = usePre ? (ushort*)d_ws : nullptr;

    (void)hipFuncSetAttribute((const void*)step_kernel,
                              hipFuncAttributeMaxDynamicSharedMemorySize, LDS_BYTES);

    init_kernel<<<dim3(BATCH * HD / 4 / 256), dim3(256), 0, stream>>>(out);
    if (usePre)
        wsplit_kernel<<<dim3(HD * HD / 8 / 256), dim3(256), 0, stream>>>(Wh, wpre);

    for (int t = 0; t < TT; ++t) {
        step_kernel<<<dim3(HD / NT, BATCH / MT), dim3(256), LDS_BYTES, stream>>>(
            x, Wh, Wx, bx, out, wpre, t);
    }
}

// Round 8
// 5360.579 us; speedup vs baseline: 6.8932x; 1.0527x over previous
//
#include <hip/hip_runtime.h>
#include <hip/hip_cooperative_groups.h>

typedef unsigned long long ull;
typedef unsigned int uint;
typedef float f32x2 __attribute__((ext_vector_type(2)));
typedef float f32x4 __attribute__((ext_vector_type(4)));
typedef uint  u32x4 __attribute__((ext_vector_type(4)));

constexpr int BATCH = 256;
constexpr int TT    = 1024;
constexpr int HD    = 512;
constexpr int PH    = 8;     // h-slice groups (wgs per batch group)
constexpr int OSL   = 64;    // outputs per wg
constexpr int ROWS  = 8;     // batch rows per wg
constexpr int HPAD  = 516;   // padded h row (floats)
constexpr int LDS_BYTES = (HD * OSL + ROWS * HPAD) * 4;  // 147584
constexpr uint SENT = 0x80000000u;   // -0.0f : unreachable by sanitized relu output

// arm out[1..1024] with the sentinel (runs before the persistent kernel each replay)
__global__ void __launch_bounds__(256, 1)
fill_kernel(uint* __restrict__ out)
{
    const size_t n = (size_t)TT * BATCH * HD / 4;          // x4 slots in out[1..1024]
    uint* base = out + (size_t)BATCH * HD;                 // skip out[0]
    u32x4 s = {SENT, SENT, SENT, SENT};
    for (size_t j = (size_t)blockIdx.x * 256 + threadIdx.x; j < n;
         j += (size_t)gridDim.x * 256)
        *(u32x4*)(base + j * 4) = s;
}

// out[0] = h0 pattern
__global__ void __launch_bounds__(256, 1)
init_kernel(float* __restrict__ out)
{
    int base = (blockIdx.x * 256 + threadIdx.x) * 4;
    int k = base & 511;
    f32x4 v = {0.f, 0.f, 0.f, 0.f};
    if (k == 0 || k == 256) v.x = 1.f;
    *(f32x4*)(out + base) = v;
}

__global__ void __launch_bounds__(256, 1)
rnn_sent_kernel(const float* __restrict__ x, const float* __restrict__ Wh,
                const float* __restrict__ Wx, const float* __restrict__ bx,
                float* __restrict__ out)
{
    extern __shared__ float lds[];
    float* whsT = lds;            // [HD][OSL] : whsT[k*64+o] = Wh[gh*64+o][k]
    float* hloc = lds + HD * OSL; // [ROWS][HPAD]

    const int tid = threadIdx.x;
    const int wid = blockIdx.x;
    const int gb  = wid & 31;     // batch group (static — correctness is placement-independent)
    const int gh  = wid >> 5;     // h-slice group

    // ---- one-time: stage transposed Wh slice (stationary for all 1024 steps) ----
    {
        const float* wsrc = Wh + (size_t)gh * OSL * HD;
        for (int idx = tid; idx < OSL * HD / 4; idx += 256) {
            int o  = idx >> 7;
            int k4 = (idx & 127) * 4;
            float4 v = *(const float4*)(wsrc + o * HD + k4);
            whsT[(k4 + 0) * OSL + o] = v.x;
            whsT[(k4 + 1) * OSL + o] = v.y;
            whsT[(k4 + 2) * OSL + o] = v.z;
            whsT[(k4 + 3) * OSL + o] = v.w;
        }
    }
    // ---- h0 in LDS (out[0] handled by init_kernel) ----
    for (int idx = tid; idx < ROWS * HD; idx += 256) {
        int rr = idx >> 9, cc = idx & 511;
        hloc[rr * HPAD + cc] = (cc == 0 || cc == HD / 2) ? 1.f : 0.f;
    }
    __syncthreads();

    // ---- thread mapping: 4 outputs x 2 rows x 128 k (identical to passing R2) ----
    const int lane = tid & 63;
    const int wv   = tid >> 6;
    const int og   = lane & 15;
    const int kc   = lane >> 4;
    const int r0   = wv * 2;
    const int o0   = og * 4;
    const int ho0  = gh * OSL + o0;

    const float wxa0 = Wx[(ho0 + 0) * 2], wxb0 = Wx[(ho0 + 0) * 2 + 1], bq0 = bx[ho0 + 0];
    const float wxa1 = Wx[(ho0 + 1) * 2], wxb1 = Wx[(ho0 + 1) * 2 + 1], bq1 = bx[ho0 + 1];
    const float wxa2 = Wx[(ho0 + 2) * 2], wxb2 = Wx[(ho0 + 2) * 2 + 1], bq2 = bx[ho0 + 2];
    const float wxa3 = Wx[(ho0 + 3) * 2], wxb3 = Wx[(ho0 + 3) * 2 + 1], bq3 = bx[ho0 + 3];

    const bool doEp = (kc < 2);
    const int  rEp  = r0 + (kc & 1);
    const int  bEp  = gb * ROWS + rEp;
    const float* xrowEp = x + (size_t)bEp * TT * 2;

    const float4* wr  = (const float4*)whsT + og;
    const float*  h0p = hloc + r0 * HPAD;
    const float*  h1p = h0p + HPAD;
    const int     kb  = kc * 128;

    const int rLd  = tid >> 5;
    const int ccLd = (tid & 31) * 2;

    for (int t = 0; t < TT; ++t) {
        float2 xv = make_float2(0.f, 0.f);
        if (doEp) xv = *(const float2*)(xrowEp + 2 * t);

        float a00 = 0.f, a01 = 0.f, a02 = 0.f, a03 = 0.f;
        float a10 = 0.f, a11 = 0.f, a12 = 0.f, a13 = 0.f;
        #pragma unroll 4
        for (int ki = 0; ki < 128; ki += 2) {
            const int k = kb + ki;
            float2 h0 = *(const float2*)(h0p + k);
            float2 h1 = *(const float2*)(h1p + k);
            float4 w0 = wr[(k + 0) * 16];
            float4 w1 = wr[(k + 1) * 16];
            a00 = fmaf(h0.x, w0.x, a00); a01 = fmaf(h0.x, w0.y, a01);
            a02 = fmaf(h0.x, w0.z, a02); a03 = fmaf(h0.x, w0.w, a03);
            a10 = fmaf(h1.x, w0.x, a10); a11 = fmaf(h1.x, w0.y, a11);
            a12 = fmaf(h1.x, w0.z, a12); a13 = fmaf(h1.x, w0.w, a13);
            a00 = fmaf(h0.y, w1.x, a00); a01 = fmaf(h0.y, w1.y, a01);
            a02 = fmaf(h0.y, w1.z, a02); a03 = fmaf(h0.y, w1.w, a03);
            a10 = fmaf(h1.y, w1.x, a10); a11 = fmaf(h1.y, w1.y, a11);
            a12 = fmaf(h1.y, w1.z, a12); a13 = fmaf(h1.y, w1.w, a13);
        }
        a00 += __shfl_xor(a00, 16); a00 += __shfl_xor(a00, 32);
        a01 += __shfl_xor(a01, 16); a01 += __shfl_xor(a01, 32);
        a02 += __shfl_xor(a02, 16); a02 += __shfl_xor(a02, 32);
        a03 += __shfl_xor(a03, 16); a03 += __shfl_xor(a03, 32);
        a10 += __shfl_xor(a10, 16); a10 += __shfl_xor(a10, 32);
        a11 += __shfl_xor(a11, 16); a11 += __shfl_xor(a11, 32);
        a12 += __shfl_xor(a12, 16); a12 += __shfl_xor(a12, 32);
        a13 += __shfl_xor(a13, 16); a13 += __shfl_xor(a13, 32);

        if (doEp) {
            const float s0 = kc ? a10 : a00;
            const float s1 = kc ? a11 : a01;
            const float s2 = kc ? a12 : a02;
            const float s3 = kc ? a13 : a03;
            float y0 = fmaxf(fmaf(xv.x, wxa0, fmaf(xv.y, wxb0, bq0)) + s0, 0.f);
            float y1 = fmaxf(fmaf(xv.x, wxa1, fmaf(xv.y, wxb1, bq1)) + s1, 0.f);
            float y2 = fmaxf(fmaf(xv.x, wxa2, fmaf(xv.y, wxb2, bq2)) + s2, 0.f);
            float y3 = fmaxf(fmaf(xv.x, wxa3, fmaf(xv.y, wxb3, bq3)) + s3, 0.f);
            // sanitize: result bit pattern must never equal the sentinel (-0.0)
            uint u0 = __float_as_uint(y0); if (u0 == SENT) u0 = 0u;
            uint u1 = __float_as_uint(y1); if (u1 == SENT) u1 = 0u;
            uint u2 = __float_as_uint(y2); if (u2 == SENT) u2 = 0u;
            uint u3 = __float_as_uint(y3); if (u3 == SENT) u3 = 0u;
            ull lo = (ull)u0 | ((ull)u1 << 32);
            ull hi = (ull)u2 | ((ull)u3 << 32);
            float* optr = out + ((size_t)(t + 1) * BATCH + bEp) * HD + ho0;
            // relaxed agent-scope stores: write-through to MALL; each 8B self-announces
            __hip_atomic_store((ull*)optr + 0, lo, __ATOMIC_RELAXED, __HIP_MEMORY_SCOPE_AGENT);
            __hip_atomic_store((ull*)optr + 1, hi, __ATOMIC_RELAXED, __HIP_MEMORY_SCOPE_AGENT);
            *(float4*)(hloc + rEp * HPAD + gh * OSL + o0) = make_float4(y0, y1, y2, y3);
        }

        if (t + 1 < TT) {
            __syncthreads();   // all waves done READING hloc for step t before exchange writes
            // value-based exchange: poll the data itself until != sentinel (no flags, no fences)
            const float* srcb = out + ((size_t)(t + 1) * BATCH + gb * ROWS + rLd) * HD + ccLd;
            float*       dst  = hloc + rLd * HPAD + ccLd;
            ull  v[7];
            int  off[7];
            #pragma unroll
            for (int p = 0; p < 7; ++p) {
                off[p] = ((gh + 1 + p) & 7) * OSL;
                v[p] = __hip_atomic_load((const ull*)(srcb + off[p]),
                                         __ATOMIC_RELAXED, __HIP_MEMORY_SCOPE_AGENT);
            }
            #pragma unroll
            for (int p = 0; p < 7; ++p) {
                while ((uint)v[p] == SENT || (uint)(v[p] >> 32) == SENT) {
                    __builtin_amdgcn_s_sleep(1);
                    v[p] = __hip_atomic_load((const ull*)(srcb + off[p]),
                                             __ATOMIC_RELAXED, __HIP_MEMORY_SCOPE_AGENT);
                }
                union { ull u; f32x2 f; } cu; cu.u = v[p];
                *(f32x2*)(dst + off[p]) = cu.f;
            }
            __syncthreads();   // exchange complete before next step's compute reads hloc
        }
    }
}

extern "C" void kernel_launch(void* const* d_in, const int* in_sizes, int n_in,
                              void* d_out, int out_size, void* d_ws, size_t ws_size,
                              hipStream_t stream) {
    const float* x  = (const float*)d_in[0];
    const float* Wh = (const float*)d_in[1];
    const float* Wx = (const float*)d_in[2];
    const float* bx = (const float*)d_in[3];
    float* out = (float*)d_out;

    (void)hipFuncSetAttribute((const void*)rnn_sent_kernel,
                              hipFuncAttributeMaxDynamicSharedMemorySize, LDS_BYTES);

    fill_kernel<<<dim3(4096), dim3(256), 0, stream>>>((uint*)out);
    init_kernel<<<dim3(BATCH * HD / 4 / 256), dim3(256), 0, stream>>>(out);

    void* args[] = { (void*)&x, (void*)&Wh, (void*)&Wx, (void*)&bx, (void*)&out };
    (void)hipLaunchCooperativeKernel((const void*)rnn_sent_kernel,
                                     dim3(32 * PH), dim3(256), args, LDS_BYTES, stream);
}

// Round 10
// 4867.690 us; speedup vs baseline: 7.5912x; 1.1013x over previous
//
#include <hip/hip_runtime.h>

typedef unsigned long long ull;
typedef unsigned int uint;
typedef unsigned short ushort;
typedef float  f32x2 __attribute__((ext_vector_type(2)));
typedef float  f32x4 __attribute__((ext_vector_type(4)));
typedef short  s16x8 __attribute__((ext_vector_type(8)));
typedef uint   u32x4 __attribute__((ext_vector_type(4)));

constexpr int BATCH = 256;
constexpr int TT    = 1024;
constexpr int HD    = 512;
constexpr int A_SZ    = 8 * HD * 2;            // 8192 B per A split (bf16 [8][512])
constexpr int ZB_OFF  = 3 * A_SZ;              // 24576: zero block (padded A rows 8..15)
constexpr int BLO_OFF = ZB_OFF + 256;          // 24832: B lo-split [64][512] bf16
constexpr int LDS_BYTES = BLO_OFF + 64 * HD * 2;   // 90368
constexpr uint SENT = 0x80000000u;             // -0.0f, unreachable by sanitized relu out

__device__ __forceinline__ ushort f2bf(float f) {
    uint u = __float_as_uint(f);
    return (ushort)((u + 0x7fffu + ((u >> 16) & 1u)) >> 16);
}
__device__ __forceinline__ float bf2f(ushort b) {
    return __uint_as_float((uint)b << 16);
}
__device__ __forceinline__ void split3(float v, ushort& h, ushort& m, ushort& l) {
    h = f2bf(v);
    float r1 = v - bf2f(h);
    m = f2bf(r1);
    float r2 = r1 - bf2f(m);
    l = f2bf(r2);
}
// R7-validated swizzle within a [rows][512] bf16 region (writer/reader consistent)
__device__ __forceinline__ uint swz(uint r, uint k) {
    return (r * 1024u + k * 2u) ^ (((r ^ (k >> 6)) & 7u) << 4);
}

__global__ void __launch_bounds__(256, 1)
fill_kernel(uint* __restrict__ out)   // arm out[1..1024] with sentinel
{
    const size_t n = (size_t)TT * BATCH * HD / 4;
    uint* base = out + (size_t)BATCH * HD;
    u32x4 s = {SENT, SENT, SENT, SENT};
    for (size_t j = (size_t)blockIdx.x * 256 + threadIdx.x; j < n;
         j += (size_t)gridDim.x * 256)
        *(u32x4*)(base + j * 4) = s;
}

__global__ void __launch_bounds__(256, 1)
init_kernel(float* __restrict__ out)  // out[0] = h0 pattern
{
    int base = (blockIdx.x * 256 + threadIdx.x) * 4;
    int k = base & 511;
    f32x4 v = {0.f, 0.f, 0.f, 0.f};
    if (k == 0 || k == 256) v.x = 1.f;
    *(f32x4*)(out + base) = v;
}

__global__ void __launch_bounds__(256, 1)
rnn_mfma2_kernel(const float* __restrict__ x, const float* __restrict__ Wh,
                 const float* __restrict__ Wx, const float* __restrict__ bx,
                 float* __restrict__ out)
{
    extern __shared__ char lds[];
    char* Ah  = lds;
    char* Am  = lds + A_SZ;
    char* Al  = lds + 2 * A_SZ;
    char* ZB  = lds + ZB_OFF;
    char* Blo = lds + BLO_OFF;

    const int tid  = threadIdx.x;
    const int wid  = blockIdx.x;
    const int gb   = wid & 31;        // batch group (8 rows)
    const int gh   = wid >> 5;        // h-slice group (64 outs)
    const int lane = tid & 63;
    const int wv   = tid >> 6;        // wave = N-tile (16 outs)
    const int m    = lane & 15;       // frag row (A) / col (B)
    const int koct = lane >> 4;
    const bool mhi = (m >= 8);        // padded A rows -> zero block

    // ---- prologue: zero A region + ZB; h0 ones ----
    for (int i = tid; i < BLO_OFF / 4; i += 256) ((uint*)lds)[i] = 0u;
    __syncthreads();
    if (tid < 16) {
        uint r = (uint)(tid & 7), k = (uint)((tid >> 3) * 256);
        *(uint*)(Ah + swz(r, k)) = 0x3F80u;   // bf16 1.0 at k, 0 at k+1
    }

    // ---- B: hi/mid splits in registers (128 VGPR), lo split into LDS ----
    s16x8 bh[16], bm[16];
    {
        const int ol = wv * 16 + m;                       // local B column 0..63
        const float* wrow = Wh + (size_t)(gh * 64 + ol) * HD;
        #pragma unroll
        for (int kt = 0; kt < 16; ++kt) {
            const float* p = wrow + kt * 32 + koct * 8;
            f32x4 v0 = *(const f32x4*)p;
            f32x4 v1 = *(const f32x4*)(p + 4);
            float vv[8] = {v0.x, v0.y, v0.z, v0.w, v1.x, v1.y, v1.z, v1.w};
            s16x8 th, tm, tl;
            #pragma unroll
            for (int j = 0; j < 8; ++j) {
                ushort hh, mm, ll; split3(vv[j], hh, mm, ll);
                th[j] = (short)hh; tm[j] = (short)mm; tl[j] = (short)ll;
            }
            bh[kt] = th; bm[kt] = tm;
            *(s16x8*)(Blo + swz((uint)ol, (uint)(kt * 32 + koct * 8))) = tl;
        }
    }

    // ---- per-lane epilogue constants ----
    const int  col  = gh * 64 + wv * 16 + m;
    const f32x2 wxv = *(const f32x2*)(Wx + col * 2);
    const float bq  = bx[col];
    const bool doEp = (lane < 32);                 // C rows 0..7 live in koct 0,1
    const int  r0   = koct * 4;                    // C/D: row = koct*4 + reg (m89)

    // ---- exchange mapping: thread = (row, col-pair) of the 8x512 h tile ----
    const int exr = tid >> 5;
    const int ccx = (tid & 31) * 2;

    __syncthreads();   // A tiles (h0) + Blo ready

    for (int t = 0; t < TT; ++t) {
        f32x2 xr[4];
        if (doEp) {
            #pragma unroll
            for (int r = 0; r < 4; ++r)
                xr[r] = *(const f32x2*)(x + ((size_t)(gb * 8 + r0 + r) * TT + t) * 2);
        }

        // ---- MFMA phase: 16 K-tiles x 6 split-products ----
        f32x4 a0 = {0,0,0,0}, a1 = {0,0,0,0}, a2 = {0,0,0,0}, a3 = {0,0,0,0};
        #pragma unroll
        for (int kt = 0; kt < 16; ++kt) {
            const uint kl = (uint)(kt * 32 + koct * 8);
            const uint ao = swz((uint)m, kl);
            s16x8 fh  = *(const s16x8*)(mhi ? ZB : (Ah + ao));
            s16x8 fm  = *(const s16x8*)(mhi ? ZB : (Am + ao));
            s16x8 fl  = *(const s16x8*)(mhi ? ZB : (Al + ao));
            s16x8 blf = *(const s16x8*)(Blo + swz((uint)(wv * 16 + m), kl));
            a0 = __builtin_amdgcn_mfma_f32_16x16x32_bf16(fh, bh[kt], a0, 0, 0, 0);
            a1 = __builtin_amdgcn_mfma_f32_16x16x32_bf16(fh, bm[kt], a1, 0, 0, 0);
            a2 = __builtin_amdgcn_mfma_f32_16x16x32_bf16(fm, bh[kt], a2, 0, 0, 0);
            a3 = __builtin_amdgcn_mfma_f32_16x16x32_bf16(fm, bm[kt], a3, 0, 0, 0);
            a1 = __builtin_amdgcn_mfma_f32_16x16x32_bf16(fh, blf,    a1, 0, 0, 0);
            a2 = __builtin_amdgcn_mfma_f32_16x16x32_bf16(fl, bh[kt], a2, 0, 0, 0);
        }
        f32x4 acc = (a0 + a1) + (a2 + a3);

        // ---- epilogue: relu, sanitize, pair adjacent cols via shfl, 8B stores (R8 parity) ----
        uint u0 = 0, u1 = 0, u2 = 0, u3 = 0;
        if (doEp) {
            float y0 = fmaxf(acc[0] + fmaf(xr[0].x, wxv.x, fmaf(xr[0].y, wxv.y, bq)), 0.f);
            float y1 = fmaxf(acc[1] + fmaf(xr[1].x, wxv.x, fmaf(xr[1].y, wxv.y, bq)), 0.f);
            float y2 = fmaxf(acc[2] + fmaf(xr[2].x, wxv.x, fmaf(xr[2].y, wxv.y, bq)), 0.f);
            float y3 = fmaxf(acc[3] + fmaf(xr[3].x, wxv.x, fmaf(xr[3].y, wxv.y, bq)), 0.f);
            u0 = __float_as_uint(y0); if (u0 == SENT) u0 = 0u;
            u1 = __float_as_uint(y1); if (u1 == SENT) u1 = 0u;
            u2 = __float_as_uint(y2); if (u2 == SENT) u2 = 0u;
            u3 = __float_as_uint(y3); if (u3 == SENT) u3 = 0u;
        }
        uint p0 = (uint)__shfl_xor((int)u0, 1);
        uint p1 = (uint)__shfl_xor((int)u1, 1);
        uint p2 = (uint)__shfl_xor((int)u2, 1);
        uint p3 = (uint)__shfl_xor((int)u3, 1);
        if (doEp && !(lane & 1)) {        // even col lane stores (own, partner) pairs
            float* obase = out + (size_t)(t + 1) * BATCH * HD;
            ull w0 = (ull)u0 | ((ull)p0 << 32);
            ull w1 = (ull)u1 | ((ull)p1 << 32);
            ull w2 = (ull)u2 | ((ull)p2 << 32);
            ull w3 = (ull)u3 | ((ull)p3 << 32);
            __hip_atomic_store((ull*)(obase + (size_t)(gb * 8 + r0 + 0) * HD + col) , w0,
                               __ATOMIC_RELAXED, __HIP_MEMORY_SCOPE_AGENT);
            __hip_atomic_store((ull*)(obase + (size_t)(gb * 8 + r0 + 1) * HD + col) , w1,
                               __ATOMIC_RELAXED, __HIP_MEMORY_SCOPE_AGENT);
            __hip_atomic_store((ull*)(obase + (size_t)(gb * 8 + r0 + 2) * HD + col) , w2,
                               __ATOMIC_RELAXED, __HIP_MEMORY_SCOPE_AGENT);
            __hip_atomic_store((ull*)(obase + (size_t)(gb * 8 + r0 + 3) * HD + col) , w3,
                               __ATOMIC_RELAXED, __HIP_MEMORY_SCOPE_AGENT);
        }

        if (t + 1 < TT) {
            __syncthreads();   // all A-frag reads of step t done (A rewrite below)
            const float* srcb = out + ((size_t)(t + 1) * BATCH + gb * 8 + exr) * HD + ccx;
            ull v[8];
            #pragma unroll
            for (int p = 0; p < 8; ++p)
                v[p] = __hip_atomic_load((const ull*)(srcb + p * 64),
                                         __ATOMIC_RELAXED, __HIP_MEMORY_SCOPE_AGENT);
            #pragma unroll
            for (int p = 0; p < 8; ++p) {
                while ((uint)v[p] == SENT || (uint)(v[p] >> 32) == SENT) {
                    __builtin_amdgcn_s_sleep(1);
                    v[p] = __hip_atomic_load((const ull*)(srcb + p * 64),
                                             __ATOMIC_RELAXED, __HIP_MEMORY_SCOPE_AGENT);
                }
            }
            #pragma unroll
            for (int p = 0; p < 8; ++p) {
                union { ull u; f32x2 f; } cu; cu.u = v[p];
                ushort h0, m0, l0, h1, m1, l1;
                split3(cu.f.x, h0, m0, l0);
                split3(cu.f.y, h1, m1, l1);
                uint off = swz((uint)exr, (uint)(p * 64 + ccx));
                *(uint*)(Ah + off) = (uint)h0 | ((uint)h1 << 16);
                *(uint*)(Am + off) = (uint)m0 | ((uint)m1 << 16);
                *(uint*)(Al + off) = (uint)l0 | ((uint)l1 << 16);
            }
            __syncthreads();   // A tiles ready for step t+1
        }
    }
}

extern "C" void kernel_launch(void* const* d_in, const int* in_sizes, int n_in,
                              void* d_out, int out_size, void* d_ws, size_t ws_size,
                              hipStream_t stream) {
    const float* x  = (const float*)d_in[0];
    const float* Wh = (const float*)d_in[1];
    const float* Wx = (const float*)d_in[2];
    const float* bx = (const float*)d_in[3];
    float* out = (float*)d_out;

    (void)hipFuncSetAttribute((const void*)rnn_mfma2_kernel,
                              hipFuncAttributeMaxDynamicSharedMemorySize, LDS_BYTES);

    fill_kernel<<<dim3(4096), dim3(256), 0, stream>>>((uint*)out);
    init_kernel<<<dim3(BATCH * HD / 4 / 256), dim3(256), 0, stream>>>(out);

    void* args[] = { (void*)&x, (void*)&Wh, (void*)&Wx, (void*)&bx, (void*)&out };
    hipError_t ce = hipLaunchCooperativeKernel((const void*)rnn_mfma2_kernel,
                                               dim3(256), dim3(256), args, LDS_BYTES, stream);
    if (ce != hipSuccess) {
        // fallback: plain launch (1 wg/CU by 90KB LDS -> all 256 co-resident in practice)
        rnn_mfma2_kernel<<<dim3(256), dim3(256), LDS_BYTES, stream>>>(x, Wh, Wx, bx, out);
    }
}